// Round 2
// baseline (315.409 us; speedup 1.0000x reference)
//
#include <hip/hip_runtime.h>

// HAttention1D: b=4,h=8,n=8192,d=64,bsz=16, levels 0..8.
// out[i] = sum_l y_l[i>>l] / (sum_l a_l[i>>l] + 1e-8); level 0: block-diagonal
// 16x16 attention; level l>=1: query block attends sibling block (B>>l)^1 on
// mean-pooled q,k (q pre-scaled d^-0.5) / sum-pooled v.
//
// R6: (a) pool remapped to float4 loads (thread owns 4 cols x 16 rows; levels
// 1..4 thread-local, 5..6 via shfl_xor, 7..8 via LDS) -- was 64 scalar dword
// loads/thread; (b) levels 5..8 deduplicated into a tiny coarse kernel (they
// were recomputed identically by 2..16 blocks each); per-block attend runs
// levels 0..4 and adds the 4 coarse rows in the epilogue (y_l[i>>l] constant
// across a 16-row block for l>=5); (c) attend has NO LDS: col-major V blocks
// make the PV fragment an 8B contiguous global load, prefetched per level.

#define NBH 32
#define SEQN 8192
#define DIM 64
#define ROWS_F16 16352   // 8192+4096+...+32 (levels 0..8)
#define YROWS 480        // coarse y rows per z: 256(l5)+128(l6)+64(l7)+32(l8)

typedef _Float16 v2h __attribute__((ext_vector_type(2)));
typedef _Float16 v4h __attribute__((ext_vector_type(4)));
typedef _Float16 v8h __attribute__((ext_vector_type(8)));
typedef float v4f __attribute__((ext_vector_type(4)));
typedef v4f v4fa __attribute__((may_alias));
typedef uint4 uint4a __attribute__((may_alias));
typedef uint2 uint2a __attribute__((may_alias));
typedef unsigned int uinta __attribute__((may_alias));

__constant__ int OFF16[9] = {0, 8192, 12288, 14336, 15360, 15872, 16128, 16256, 16320};

// ---------------- pool ----------------
// mode (blockIdx.z): 0=q (mean, *0.125), 1=k (mean), 2=v (sum, col-major blocks).
// Thread t: cols d4..d4+3 (d4=(t&15)*4), rows rgrp*16..+15 (rgrp=t>>4) of a
// 256-row chunk. Loads: 16x float4. Levels 1..4 pooled thread-locally; level 5
// via shfl_xor(16), level 6 via shfl_xor(32), levels 7..8 via LDS.
__global__ __launch_bounds__(256) void pool_kernel(
    const float* __restrict__ q, const float* __restrict__ k, const float* __restrict__ v,
    _Float16* __restrict__ qp, _Float16* __restrict__ kp, _Float16* __restrict__ vp) {
    const int chunk = blockIdx.x, z = blockIdx.y, mode = blockIdx.z;
    const int t = threadIdx.x;
    const int d4i = t & 15, d4 = d4i * 4, rgrp = t >> 4;
    const float* __restrict__ in = (mode == 0) ? q : (mode == 1) ? k : v;
    _Float16* __restrict__ pyr = (mode == 0) ? qp : (mode == 1) ? kp : vp;
    const float fs = (mode == 0) ? 0.125f : 1.0f;   // fine-level scale (d^-0.5)
    const float sc = (mode == 2) ? 1.0f : 0.5f;     // pool scale (sum vs mean)
    const bool vlay = (mode == 2);
    __shared__ float lds[4][64];
    const int row16 = chunk * 256 + rgrp * 16;
    const size_t zb = (size_t)z * ROWS_F16;

    v4f val[16];
    {
        const v4fa* src = (const v4fa*)(in + ((size_t)z * SEQN + row16) * DIM) + d4i;
#pragma unroll
        for (int r = 0; r < 16; ++r) val[r] = src[r * 16] * fs;
    }

    // ---- fine level ----
    if (!vlay) {
        _Float16* dst = pyr + (zb + row16) * DIM + d4;
#pragma unroll
        for (int r = 0; r < 16; ++r) {
            v4h h;
#pragma unroll
            for (int i = 0; i < 4; ++i) h[i] = (_Float16)val[r][i];
            *(uint2a*)(dst + (size_t)r * DIM) = __builtin_bit_cast(uint2, h);
        }
    } else {
        // col-major block [col][16 rows]; thread's patch = 128B contiguous
        _Float16* dst = pyr + (zb + row16) * DIM + d4 * 16;
#pragma unroll
        for (int c = 0; c < 4; ++c) {
            v8h h0, h1;
#pragma unroll
            for (int i = 0; i < 8; ++i) {
                h0[i] = (_Float16)val[i][c];
                h1[i] = (_Float16)val[8 + i][c];
            }
            *(uint4a*)(dst + c * 16) = __builtin_bit_cast(uint4, h0);
            *(uint4a*)(dst + c * 16 + 8) = __builtin_bit_cast(uint4, h1);
        }
    }

    // ---- levels 1..4 (thread-local) ----
#pragma unroll
    for (int l = 1; l <= 4; ++l) {
        const int nr = 16 >> l;
#pragma unroll
        for (int r = 0; r < nr; ++r) val[r] = (val[2 * r] + val[2 * r + 1]) * sc;
        const int row0 = row16 >> l;
        if (!vlay) {
            _Float16* dst = pyr + (zb + OFF16[l] + row0) * DIM + d4;
#pragma unroll
            for (int r = 0; r < nr; ++r) {
                v4h h;
#pragma unroll
                for (int i = 0; i < 4; ++i) h[i] = (_Float16)val[r][i];
                *(uint2a*)(dst + (size_t)r * DIM) = __builtin_bit_cast(uint2, h);
            }
        } else {
            const int r4 = row0 & 15;
            _Float16* dst = pyr + (zb + OFF16[l] + (row0 & ~15)) * DIM + r4;
#pragma unroll
            for (int c = 0; c < 4; ++c) {
                _Float16* dc = dst + (d4 + c) * 16;
                if (nr == 8) {
                    v8h h;
#pragma unroll
                    for (int i = 0; i < 8; ++i) h[i] = (_Float16)val[i][c];
                    *(uint4a*)dc = __builtin_bit_cast(uint4, h);
                } else if (nr == 4) {
                    v4h h;
#pragma unroll
                    for (int i = 0; i < 4; ++i) h[i] = (_Float16)val[i][c];
                    *(uint2a*)dc = __builtin_bit_cast(uint2, h);
                } else if (nr == 2) {
                    v2h h;
                    h[0] = (_Float16)val[0][c];
                    h[1] = (_Float16)val[1][c];
                    *(uinta*)dc = __builtin_bit_cast(unsigned int, h);
                } else {
                    *dc = (_Float16)val[0][c];
                }
            }
        }
    }

    // ---- level 5 (shfl_xor 16: pairs of rgrp) ----
    v4f v5, v6;
#pragma unroll
    for (int c = 0; c < 4; ++c) v5[c] = __shfl_xor(val[0][c], 16, 64);
    v5 = (val[0] + v5) * sc;
    const int row5 = row16 >> 5;
    if ((rgrp & 1) == 0) {
        if (!vlay) {
            v4h h;
#pragma unroll
            for (int i = 0; i < 4; ++i) h[i] = (_Float16)v5[i];
            *(uint2a*)(pyr + (zb + OFF16[5] + row5) * DIM + d4) = __builtin_bit_cast(uint2, h);
        } else {
            const int r4 = row5 & 15;
            _Float16* dst = pyr + (zb + OFF16[5] + (row5 & ~15)) * DIM + r4;
#pragma unroll
            for (int c = 0; c < 4; ++c) dst[(d4 + c) * 16] = (_Float16)v5[c];
        }
    }
    // ---- level 6 (shfl_xor 32) ----
#pragma unroll
    for (int c = 0; c < 4; ++c) v6[c] = __shfl_xor(v5[c], 32, 64);
    v6 = (v5 + v6) * sc;
    const int row6 = row16 >> 6;
    if ((rgrp & 3) == 0) {
        if (!vlay) {
            v4h h;
#pragma unroll
            for (int i = 0; i < 4; ++i) h[i] = (_Float16)v6[i];
            *(uint2a*)(pyr + (zb + OFF16[6] + row6) * DIM + d4) = __builtin_bit_cast(uint2, h);
        } else {
            const int r4 = row6 & 15;
            _Float16* dst = pyr + (zb + OFF16[6] + (row6 & ~15)) * DIM + r4;
#pragma unroll
            for (int c = 0; c < 4; ++c) dst[(d4 + c) * 16] = (_Float16)v6[c];
        }
#pragma unroll
        for (int c = 0; c < 4; ++c) lds[rgrp >> 2][d4 + c] = v6[c];
    }
    __syncthreads();
    // ---- levels 7,8 (cross-wave via LDS) ----
    if (t < 64) {
        const float l7a = (lds[0][t] + lds[1][t]) * sc;
        const float l7b = (lds[2][t] + lds[3][t]) * sc;
        const float l8v = (l7a + l7b) * sc;
        const int a7 = chunk * 2, a8 = chunk;
        if (!vlay) {
            _Float16* d7 = pyr + (zb + OFF16[7] + a7) * DIM + t;
            d7[0] = (_Float16)l7a;
            d7[DIM] = (_Float16)l7b;
            pyr[(zb + OFF16[8] + a8) * DIM + t] = (_Float16)l8v;
        } else {
            v2h h;
            h[0] = (_Float16)l7a;
            h[1] = (_Float16)l7b;
            *(uinta*)(pyr + (zb + OFF16[7] + (a7 & ~15)) * DIM + t * 16 + (a7 & 15)) =
                __builtin_bit_cast(unsigned int, h);
            pyr[(zb + OFF16[8] + (a8 & ~15)) * DIM + t * 16 + (a8 & 15)] = (_Float16)l8v;
        }
    }
}

// ---------------- attend ----------------
__device__ __forceinline__ float bperm(int lane, float x) {
    return __int_as_float(__builtin_amdgcn_ds_bpermute(lane << 2, __float_as_int(x)));
}

// 256 threads = 4 independent waves; wave w handles output block B = bx*4+w.
// All operands direct global->VGPR (q/k row fragments 16B; V col-major block ->
// PV fragment is 8B contiguous). No LDS. COARSE: levels 0..4 here, 5..8 from
// the coarse kernel's y/a buffer (constant per block since i>>l == B>>(l-4)>>..).
template <bool COARSE>
__global__ __launch_bounds__(256) void attend_kernel(
    const _Float16* __restrict__ qp, const _Float16* __restrict__ kp,
    const _Float16* __restrict__ vp, const float* __restrict__ yc,
    const float* __restrict__ ac, float* __restrict__ out) {
    const int tid = threadIdx.x;
    const int t = tid & 63, w = tid >> 6;
    const int m = t & 15, quad = t >> 4;
    const int B = blockIdx.x * 4 + w;
    const int z = blockIdx.y;
    const size_t zp = (size_t)z * ROWS_F16 * DIM;
    constexpr int LMAX = COARSE ? 4 : 8;

    v4f Y[4];
    float A[4];
#pragma unroll
    for (int nt = 0; nt < 4; ++nt) Y[nt] = (v4f){0.f, 0.f, 0.f, 0.f};
#pragma unroll
    for (int r = 0; r < 4; ++r) A[r] = 0.f;

    auto issue = [&](int l, v8h& qf0, v8h& qf1, v8h& kf0, v8h& kf1, uint2 (&vf)[4]) {
        const int c = (l == 0) ? 16 : ((l <= 4) ? (16 >> l) : 1);
        const int qrow0 = (B * 16) >> l;
        const int kb = (l == 0) ? B : ((B >> l) ^ 1);
        const int qm = (m < c) ? m : (c - 1);  // clamp: duplicate valid rows
        const uint4a* qr = (const uint4a*)(qp + zp + (size_t)(OFF16[l] + qrow0 + qm) * DIM);
        qf0 = __builtin_bit_cast(v8h, qr[quad]);
        qf1 = __builtin_bit_cast(v8h, qr[4 + quad]);
        const uint4a* kr = (const uint4a*)(kp + zp + (size_t)(OFF16[l] + kb * 16 + m) * DIM);
        kf0 = __builtin_bit_cast(v8h, kr[quad]);
        kf1 = __builtin_bit_cast(v8h, kr[4 + quad]);
        const _Float16* vb = vp + zp + (size_t)(OFF16[l] + kb * 16) * DIM;
#pragma unroll
        for (int nt = 0; nt < 4; ++nt)
            vf[nt] = *(const uint2a*)(vb + (nt * 16 + m) * 16 + quad * 4);
    };

    auto do_level = [&](int l, v8h qf0, v8h qf1, v8h kf0, v8h kf1, const uint2 (&vf)[4]) {
        // S^T[j][m] = sum_d K[j][d]*Qs[m][d]; A-frag rows = K, B-frag rows = Q.
        v4f s4 = (v4f){0.f, 0.f, 0.f, 0.f};
        s4 = __builtin_amdgcn_mfma_f32_16x16x32_f16(kf0, qf0, s4, 0, 0, 0);
        s4 = __builtin_amdgcn_mfma_f32_16x16x32_f16(kf1, qf1, s4, 0, 0, 0);
        float mx = fmaxf(fmaxf(s4[0], s4[1]), fmaxf(s4[2], s4[3]));
        mx = fmaxf(mx, __shfl_xor(mx, 16, 64));
        mx = fmaxf(mx, __shfl_xor(mx, 32, 64));
        float e0 = __expf(s4[0] - mx), e1 = __expf(s4[1] - mx);
        float e2 = __expf(s4[2] - mx), e3 = __expf(s4[3] - mx);
        float sm = e0 + e1 + e2 + e3;
        sm += __shfl_xor(sm, 16, 64);
        sm += __shfl_xor(sm, 32, 64);
        const int sl = (m >> l) + (quad << 4);
        v4h pf;
        pf[0] = (_Float16)bperm(sl, e0);
        pf[1] = (_Float16)bperm(sl, e1);
        pf[2] = (_Float16)bperm(sl, e2);
        pf[3] = (_Float16)bperm(sl, e3);
#pragma unroll
        for (int nt = 0; nt < 4; ++nt)
            Y[nt] = __builtin_amdgcn_mfma_f32_16x16x16f16(pf, __builtin_bit_cast(v4h, vf[nt]),
                                                          Y[nt], 0, 0, 0);
#pragma unroll
        for (int r = 0; r < 4; ++r) A[r] += bperm((quad * 4 + r) >> l, sm);
    };

    v8h q0{}, q1{}, k0{}, k1{};
    uint2 vf[4] = {};
    issue(0, q0, q1, k0, k1, vf);
#pragma unroll
    for (int l = 0; l <= LMAX; ++l) {
        v8h nq0{}, nq1{}, nk0{}, nk1{};
        uint2 nvf[4] = {};
        if (l < LMAX) issue(l + 1, nq0, nq1, nk0, nk1, nvf);
        do_level(l, q0, q1, k0, k1, vf);
        q0 = nq0; q1 = nq1; k0 = nk0; k1 = nk1;
#pragma unroll
        for (int i = 0; i < 4; ++i) vf[i] = nvf[i];
    }

    // ---- epilogue ----
    float extraA = 0.f;
    float yext[4] = {0.f, 0.f, 0.f, 0.f};
    if (COARSE) {
        const float* yb = yc + (size_t)z * YROWS * 64;
        const float* ab = ac + (size_t)z * YROWS;
        const int o5 = (B >> 1), o6 = 256 + (B >> 2), o7 = 384 + (B >> 3), o8 = 448 + (B >> 4);
        extraA = ab[o5] + ab[o6] + ab[o7] + ab[o8];
#pragma unroll
        for (int nt = 0; nt < 4; ++nt) {
            const int col = nt * 16 + m;
            yext[nt] = yb[o5 * 64 + col] + yb[o6 * 64 + col] + yb[o7 * 64 + col] + yb[o8 * 64 + col];
        }
    }
    float* ob = out + (size_t)z * SEQN * DIM + (size_t)B * 16 * DIM;
#pragma unroll
    for (int r = 0; r < 4; ++r) {
        const float inv = 1.0f / (A[r] + extraA + 1e-8f);
#pragma unroll
        for (int nt = 0; nt < 4; ++nt)
            ob[(quad * 4 + r) * 64 + nt * 16 + m] = (Y[nt][r] + yext[nt]) * inv;
    }
}

// ---------------- coarse (levels 5..8, once per z) ----------------
// Tile tl at level l = pooled q-rows tl*16..+15, all sharing k-block tl^1 (for
// fine block B in tile: (B>>l)^1 == (p>>4)^1 == tl^1). 30 tiles per z.
__global__ __launch_bounds__(64) void coarse_kernel(
    const _Float16* __restrict__ qp, const _Float16* __restrict__ kp,
    const _Float16* __restrict__ vp, float* __restrict__ yc, float* __restrict__ ac) {
    const int t = threadIdx.x, m = t & 15, quad = t >> 4;
    const int u = blockIdx.x, z = blockIdx.y;
    int l, tl, co;
    if (u < 16)      { l = 5; tl = u;      co = 0;   }
    else if (u < 24) { l = 6; tl = u - 16; co = 256; }
    else if (u < 28) { l = 7; tl = u - 24; co = 384; }
    else             { l = 8; tl = u - 28; co = 448; }
    const int kb = tl ^ 1;
    const size_t zp = (size_t)z * ROWS_F16 * DIM;

    const uint4a* qr = (const uint4a*)(qp + zp + (size_t)(OFF16[l] + tl * 16 + m) * DIM);
    const v8h qf0 = __builtin_bit_cast(v8h, qr[quad]);
    const v8h qf1 = __builtin_bit_cast(v8h, qr[4 + quad]);
    const uint4a* kr = (const uint4a*)(kp + zp + (size_t)(OFF16[l] + kb * 16 + m) * DIM);
    const v8h kf0 = __builtin_bit_cast(v8h, kr[quad]);
    const v8h kf1 = __builtin_bit_cast(v8h, kr[4 + quad]);
    const _Float16* vb = vp + zp + (size_t)(OFF16[l] + kb * 16) * DIM;
    uint2 vf[4];
#pragma unroll
    for (int nt = 0; nt < 4; ++nt)
        vf[nt] = *(const uint2a*)(vb + (nt * 16 + m) * 16 + quad * 4);

    v4f s4 = (v4f){0.f, 0.f, 0.f, 0.f};
    s4 = __builtin_amdgcn_mfma_f32_16x16x32_f16(kf0, qf0, s4, 0, 0, 0);
    s4 = __builtin_amdgcn_mfma_f32_16x16x32_f16(kf1, qf1, s4, 0, 0, 0);
    float mx = fmaxf(fmaxf(s4[0], s4[1]), fmaxf(s4[2], s4[3]));
    mx = fmaxf(mx, __shfl_xor(mx, 16, 64));
    mx = fmaxf(mx, __shfl_xor(mx, 32, 64));
    float e0 = __expf(s4[0] - mx), e1 = __expf(s4[1] - mx);
    float e2 = __expf(s4[2] - mx), e3 = __expf(s4[3] - mx);
    float sm = e0 + e1 + e2 + e3;
    sm += __shfl_xor(sm, 16, 64);
    sm += __shfl_xor(sm, 32, 64);
    const int sl = m + (quad << 4);  // 16 distinct q-rows: l=0 pattern
    v4h pf;
    pf[0] = (_Float16)bperm(sl, e0);
    pf[1] = (_Float16)bperm(sl, e1);
    pf[2] = (_Float16)bperm(sl, e2);
    pf[3] = (_Float16)bperm(sl, e3);
    v4f Yt[4];
#pragma unroll
    for (int nt = 0; nt < 4; ++nt) {
        Yt[nt] = (v4f){0.f, 0.f, 0.f, 0.f};
        Yt[nt] = __builtin_amdgcn_mfma_f32_16x16x16f16(pf, __builtin_bit_cast(v4h, vf[nt]),
                                                       Yt[nt], 0, 0, 0);
    }
    float Ar[4];
#pragma unroll
    for (int r = 0; r < 4; ++r) Ar[r] = bperm(quad * 4 + r, sm);

    float* yb = yc + ((size_t)z * YROWS + co + tl * 16) * 64;
#pragma unroll
    for (int r = 0; r < 4; ++r)
#pragma unroll
        for (int nt = 0; nt < 4; ++nt)
            yb[(quad * 4 + r) * 64 + nt * 16 + m] = Yt[nt][r];
    if (m == 0) {
#pragma unroll
        for (int r = 0; r < 4; ++r)
            ac[(size_t)z * YROWS + co + tl * 16 + quad * 4 + r] = Ar[r];
    }
}

extern "C" void kernel_launch(void* const* d_in, const int* in_sizes, int n_in,
                              void* d_out, int out_size, void* d_ws, size_t ws_size,
                              hipStream_t stream) {
    const float* q = (const float*)d_in[0];
    const float* k = (const float*)d_in[1];
    const float* v = (const float*)d_in[2];
    float* out = (float*)d_out;

    const size_t T16 = (size_t)NBH * ROWS_F16 * DIM * sizeof(_Float16);  // 66,977,792
    const size_t YCB = (size_t)NBH * YROWS * 64 * sizeof(float);         // 3,932,160
    const size_t ACB = (size_t)NBH * YROWS * sizeof(float);              // 61,440
    char* wsp = (char*)d_ws;
    _Float16* qp = (_Float16*)wsp;
    _Float16* kp = (_Float16*)(wsp + T16);
    _Float16* vp = (_Float16*)(wsp + 2 * T16);

    pool_kernel<<<dim3(SEQN / 256, NBH, 3), 256, 0, stream>>>(q, k, v, qp, kp, vp);
    if (ws_size >= 3 * T16 + YCB + ACB) {
        float* yc = (float*)(wsp + 3 * T16);
        float* ac = (float*)(wsp + 3 * T16 + YCB);
        coarse_kernel<<<dim3(30, NBH), 64, 0, stream>>>(qp, kp, vp, yc, ac);
        attend_kernel<true><<<dim3(SEQN / 64, NBH), 256, 0, stream>>>(qp, kp, vp, yc, ac, out);
    } else {
        attend_kernel<false><<<dim3(SEQN / 64, NBH), 256, 0, stream>>>(qp, kp, vp, nullptr,
                                                                       nullptr, out);
    }
}

// Round 3
// 308.470 us; speedup vs baseline: 1.0225x; 1.0225x over previous
//
#include <hip/hip_runtime.h>

// HAttention1D: b=4,h=8,n=8192,d=64,bsz=16, levels 0..8.
// out[i] = sum_l y_l[i>>l] / (sum_l a_l[i>>l] + 1e-8); level 0: block-diagonal
// 16x16 attention; level l>=1: query block attends sibling block (B>>l)^1 on
// mean-pooled q,k (q pre-scaled d^-0.5) / sum-pooled v.
//
// R7: byte-reduction round. Pool no longer materializes fine-level q/k fp16
// (-134 MB of writes+rereads): attend builds level-0 Q/K fragments directly
// from fp32 inputs (2x float4 + cvt, bit-identical rounding). V keeps fp16
// col-major fine (33 MB) for the 8B PV fragment. Pool back to the best-measured
// column-walk load pattern (R4's 100us structure), with col-major V stores now
// vectorized (16 contiguous halves per block = 2x uint4). Coarse dedup kernel
// (levels 5..8 once per z) retained from R6.

#define NBH 32
#define SEQN 8192
#define DIM 64
#define ROWS_CMP 8160    // coarse rows per z: 4096+2048+...+32 (levels 1..8)
#define ROWS_V 16352     // v: 8192 fine + 8160 coarse
#define YROWS 480        // coarse y rows per z: 256(l5)+128(l6)+64(l7)+32(l8)

typedef _Float16 v2h __attribute__((ext_vector_type(2)));
typedef _Float16 v4h __attribute__((ext_vector_type(4)));
typedef _Float16 v8h __attribute__((ext_vector_type(8)));
typedef float v4f __attribute__((ext_vector_type(4)));
typedef float4 float4a __attribute__((may_alias));
typedef uint4 uint4a __attribute__((may_alias));
typedef uint2 uint2a __attribute__((may_alias));
typedef unsigned int uinta __attribute__((may_alias));

// coarse level offsets (rows), OFF8[0] unused
__constant__ int OFF8[9] = {0, 0, 4096, 6144, 7168, 7680, 7936, 8064, 8128};

// ---------------- pool ----------------
// mode (blockIdx.z): 0=q (mean, *0.125), 1=k (mean), 2=v (sum, col-major blocks,
// fine+coarse). q/k: coarse only, row-major. Thread owns column d (t&63), rows
// g*64..+63 (g=t>>6) of a 256-row chunk: 64 coalesced scalar loads (R4-proven).
__global__ __launch_bounds__(256) void pool_kernel(
    const float* __restrict__ q, const float* __restrict__ k, const float* __restrict__ v,
    _Float16* __restrict__ qp, _Float16* __restrict__ kp, _Float16* __restrict__ vp) {
    const int chunk = blockIdx.x, z = blockIdx.y, mode = blockIdx.z;
    const int t = threadIdx.x, d = t & 63, g = t >> 6;
    const float* __restrict__ in = (mode == 0) ? q : (mode == 1) ? k : v;
    _Float16* __restrict__ pyr = (mode == 0) ? qp : (mode == 1) ? kp : vp;
    const float sc = (mode == 2) ? 1.0f : 0.5f;   // pool scale (sum vs mean)
    const bool vlay = (mode == 2);
    const size_t zb = (size_t)z * (vlay ? ROWS_V : ROWS_CMP);
    const int cbase = vlay ? SEQN : 0;            // v coarse rows start after fine
    __shared__ float lds[4][64];
    const int rowbase = chunk * 256 + g * 64;

    float val[64];
    {
        const float* src = in + ((size_t)z * SEQN + rowbase) * DIM + d;
        if (mode == 0) {
#pragma unroll
            for (int r = 0; r < 64; ++r) val[r] = src[(size_t)r * DIM] * 0.125f;
        } else {
#pragma unroll
            for (int r = 0; r < 64; ++r) val[r] = src[(size_t)r * DIM];
        }
    }

    // ---- v fine (col-major 16-row blocks): 4 blocks x 16 contiguous halves ----
    if (vlay) {
#pragma unroll
        for (int b = 0; b < 4; ++b) {
            v8h h0, h1;
#pragma unroll
            for (int i = 0; i < 8; ++i) {
                h0[i] = (_Float16)val[b * 16 + i];
                h1[i] = (_Float16)val[b * 16 + 8 + i];
            }
            _Float16* dst = pyr + (zb + rowbase + b * 16) * DIM + d * 16;
            *(uint4a*)dst = __builtin_bit_cast(uint4, h0);
            *(uint4a*)(dst + 8) = __builtin_bit_cast(uint4, h1);
        }
    }

    // ---- levels 1..6 (thread-local over this 64-row group) ----
#pragma unroll
    for (int l = 1; l <= 6; ++l) {
        const int nr = 64 >> l;
#pragma unroll
        for (int r = 0; r < nr; ++r) val[r] = (val[2 * r] + val[2 * r + 1]) * sc;
        const int row0 = rowbase >> l;
        if (!vlay) {
            _Float16* dst = pyr + (zb + OFF8[l] + row0) * DIM + d;
#pragma unroll
            for (int r = 0; r < nr; ++r) dst[(size_t)r * DIM] = (_Float16)val[r];
        } else {
            if (nr >= 16) {
#pragma unroll
                for (int b = 0; b < nr / 16; ++b) {
                    v8h h0, h1;
#pragma unroll
                    for (int i = 0; i < 8; ++i) {
                        h0[i] = (_Float16)val[b * 16 + i];
                        h1[i] = (_Float16)val[b * 16 + 8 + i];
                    }
                    _Float16* dst = pyr + (zb + cbase + OFF8[l] + row0 + b * 16) * DIM + d * 16;
                    *(uint4a*)dst = __builtin_bit_cast(uint4, h0);
                    *(uint4a*)(dst + 8) = __builtin_bit_cast(uint4, h1);
                }
            } else {
                const int r4 = row0 & 15;
                _Float16* dst = pyr + (zb + cbase + OFF8[l] + (row0 & ~15)) * DIM + d * 16 + r4;
                if (nr == 8) {           // r4 in {0,8}: 16B aligned
                    v8h h;
#pragma unroll
                    for (int i = 0; i < 8; ++i) h[i] = (_Float16)val[i];
                    *(uint4a*)dst = __builtin_bit_cast(uint4, h);
                } else if (nr == 4) {    // r4 = g*4: 8B aligned
                    v4h h;
#pragma unroll
                    for (int i = 0; i < 4; ++i) h[i] = (_Float16)val[i];
                    *(uint2a*)dst = __builtin_bit_cast(uint2, h);
                } else if (nr == 2) {    // r4 = g*2: 4B aligned
                    v2h h;
                    h[0] = (_Float16)val[0];
                    h[1] = (_Float16)val[1];
                    *(uinta*)dst = __builtin_bit_cast(unsigned int, h);
                } else {                 // nr == 1 (level 6)
                    dst[0] = (_Float16)val[0];
                }
            }
        }
    }

    // ---- levels 7,8 (cross-group via LDS; val[0] holds this group's level-6) ----
    lds[g][d] = val[0];
    __syncthreads();
    if (t < 64) {
        const float l7a = (lds[0][t] + lds[1][t]) * sc;
        const float l7b = (lds[2][t] + lds[3][t]) * sc;
        const float l8v = (l7a + l7b) * sc;
        const int a7 = chunk * 2;
        if (!vlay) {
            _Float16* d7 = pyr + (zb + OFF8[7] + a7) * DIM + t;
            d7[0] = (_Float16)l7a;
            d7[DIM] = (_Float16)l7b;
            pyr[(zb + OFF8[8] + chunk) * DIM + t] = (_Float16)l8v;
        } else {
            v2h h;
            h[0] = (_Float16)l7a;
            h[1] = (_Float16)l7b;
            *(uinta*)(pyr + (zb + cbase + OFF8[7] + (a7 & ~15)) * DIM + t * 16 + (a7 & 15)) =
                __builtin_bit_cast(unsigned int, h);
            pyr[(zb + cbase + OFF8[8] + (chunk & ~15)) * DIM + t * 16 + (chunk & 15)] =
                (_Float16)l8v;
        }
    }
}

// ---------------- attend ----------------
__device__ __forceinline__ float bperm(int lane, float x) {
    return __int_as_float(__builtin_amdgcn_ds_bpermute(lane << 2, __float_as_int(x)));
}

// 256 threads = 4 independent waves; wave w handles output block B = bx*4+w.
// No LDS. Level 0: Q/K fragments straight from fp32 inputs (2x float4 + cvt,
// rounding identical to pooled-fp16 path), V from fp16 col-major fine. Levels
// 1..4 from coarse pyramid; 5..8 added in epilogue from coarse kernel output.
template <bool COARSE>
__global__ __launch_bounds__(256) void attend_kernel(
    const float* __restrict__ qg, const float* __restrict__ kg, const float* __restrict__ vg,
    const _Float16* __restrict__ qp, const _Float16* __restrict__ kp,
    const _Float16* __restrict__ vp, const float* __restrict__ yc,
    const float* __restrict__ ac, float* __restrict__ out) {
    const int tid = threadIdx.x;
    const int t = tid & 63, w = tid >> 6;
    const int m = t & 15, quad = t >> 4;
    const int B = blockIdx.x * 4 + w;
    const int z = blockIdx.y;
    const size_t zp8 = (size_t)z * ROWS_CMP * DIM;
    const size_t zpv = (size_t)z * ROWS_V * DIM;
    const size_t zf = (size_t)z * SEQN * DIM;
    constexpr int LMAX = COARSE ? 4 : 8;

    v4f Y[4];
    float A[4];
#pragma unroll
    for (int nt = 0; nt < 4; ++nt) Y[nt] = (v4f){0.f, 0.f, 0.f, 0.f};
#pragma unroll
    for (int r = 0; r < 4; ++r) A[r] = 0.f;

    auto issue = [&](int l, v8h& qf0, v8h& qf1, v8h& kf0, v8h& kf1, uint2 (&vfr)[4]) {
        if (l == 0) {
            const float4a* qr = (const float4a*)(qg + zf + (size_t)(B * 16 + m) * DIM + quad * 8);
            const float4 qa0 = qr[0], qa1 = qr[1], qb0 = qr[8], qb1 = qr[9];
            const float4a* kr = (const float4a*)(kg + zf + (size_t)(B * 16 + m) * DIM + quad * 8);
            const float4 ka0 = kr[0], ka1 = kr[1], kb0 = kr[8], kb1 = kr[9];
            v8h h;
            h[0] = (_Float16)(qa0.x * 0.125f); h[1] = (_Float16)(qa0.y * 0.125f);
            h[2] = (_Float16)(qa0.z * 0.125f); h[3] = (_Float16)(qa0.w * 0.125f);
            h[4] = (_Float16)(qa1.x * 0.125f); h[5] = (_Float16)(qa1.y * 0.125f);
            h[6] = (_Float16)(qa1.z * 0.125f); h[7] = (_Float16)(qa1.w * 0.125f);
            qf0 = h;
            h[0] = (_Float16)(qb0.x * 0.125f); h[1] = (_Float16)(qb0.y * 0.125f);
            h[2] = (_Float16)(qb0.z * 0.125f); h[3] = (_Float16)(qb0.w * 0.125f);
            h[4] = (_Float16)(qb1.x * 0.125f); h[5] = (_Float16)(qb1.y * 0.125f);
            h[6] = (_Float16)(qb1.z * 0.125f); h[7] = (_Float16)(qb1.w * 0.125f);
            qf1 = h;
            h[0] = (_Float16)ka0.x; h[1] = (_Float16)ka0.y;
            h[2] = (_Float16)ka0.z; h[3] = (_Float16)ka0.w;
            h[4] = (_Float16)ka1.x; h[5] = (_Float16)ka1.y;
            h[6] = (_Float16)ka1.z; h[7] = (_Float16)ka1.w;
            kf0 = h;
            h[0] = (_Float16)kb0.x; h[1] = (_Float16)kb0.y;
            h[2] = (_Float16)kb0.z; h[3] = (_Float16)kb0.w;
            h[4] = (_Float16)kb1.x; h[5] = (_Float16)kb1.y;
            h[6] = (_Float16)kb1.z; h[7] = (_Float16)kb1.w;
            kf1 = h;
            const float* vb = vg + zf + (size_t)(B * 16) * DIM;
#pragma unroll
            for (int nt = 0; nt < 4; ++nt) {
                v4h hv;
#pragma unroll
                for (int i = 0; i < 4; ++i)
                    hv[i] = (_Float16)vb[(quad * 4 + i) * DIM + nt * 16 + m];
                vfr[nt] = __builtin_bit_cast(uint2, hv);
            }
        } else {
            const int c = (l <= 4) ? (16 >> l) : 1;
            const int qrow0 = (B * 16) >> l;
            const int kb = (B >> l) ^ 1;
            const int qm = (m < c) ? m : (c - 1);  // clamp: duplicate valid rows
            const uint4a* qr = (const uint4a*)(qp + zp8 + (size_t)(OFF8[l] + qrow0 + qm) * DIM);
            qf0 = __builtin_bit_cast(v8h, qr[quad]);
            qf1 = __builtin_bit_cast(v8h, qr[4 + quad]);
            const uint4a* kr = (const uint4a*)(kp + zp8 + (size_t)(OFF8[l] + kb * 16 + m) * DIM);
            kf0 = __builtin_bit_cast(v8h, kr[quad]);
            kf1 = __builtin_bit_cast(v8h, kr[4 + quad]);
            const _Float16* vb = vp + zpv + (size_t)(SEQN + OFF8[l] + kb * 16) * DIM;
#pragma unroll
            for (int nt = 0; nt < 4; ++nt)
                vfr[nt] = *(const uint2a*)(vb + (nt * 16 + m) * 16 + quad * 4);
        }
    };

    auto do_level = [&](int l, v8h qf0, v8h qf1, v8h kf0, v8h kf1, const uint2 (&vfr)[4]) {
        // S^T[j][m] = sum_d K[j][d]*Qs[m][d]; A-frag rows = K, B-frag rows = Q.
        v4f s4 = (v4f){0.f, 0.f, 0.f, 0.f};
        s4 = __builtin_amdgcn_mfma_f32_16x16x32_f16(kf0, qf0, s4, 0, 0, 0);
        s4 = __builtin_amdgcn_mfma_f32_16x16x32_f16(kf1, qf1, s4, 0, 0, 0);
        float mx = fmaxf(fmaxf(s4[0], s4[1]), fmaxf(s4[2], s4[3]));
        mx = fmaxf(mx, __shfl_xor(mx, 16, 64));
        mx = fmaxf(mx, __shfl_xor(mx, 32, 64));
        float e0 = __expf(s4[0] - mx), e1 = __expf(s4[1] - mx);
        float e2 = __expf(s4[2] - mx), e3 = __expf(s4[3] - mx);
        float sm = e0 + e1 + e2 + e3;
        sm += __shfl_xor(sm, 16, 64);
        sm += __shfl_xor(sm, 32, 64);
        const int sl = (m >> l) + (quad << 4);
        v4h pf;
        pf[0] = (_Float16)bperm(sl, e0);
        pf[1] = (_Float16)bperm(sl, e1);
        pf[2] = (_Float16)bperm(sl, e2);
        pf[3] = (_Float16)bperm(sl, e3);
#pragma unroll
        for (int nt = 0; nt < 4; ++nt)
            Y[nt] = __builtin_amdgcn_mfma_f32_16x16x16f16(pf, __builtin_bit_cast(v4h, vfr[nt]),
                                                          Y[nt], 0, 0, 0);
#pragma unroll
        for (int r = 0; r < 4; ++r) A[r] += bperm((quad * 4 + r) >> l, sm);
    };

    v8h q0{}, q1{}, k0{}, k1{};
    uint2 vf[4] = {};
    issue(0, q0, q1, k0, k1, vf);
#pragma unroll
    for (int l = 0; l <= LMAX; ++l) {
        v8h nq0{}, nq1{}, nk0{}, nk1{};
        uint2 nvf[4] = {};
        if (l < LMAX) issue(l + 1, nq0, nq1, nk0, nk1, nvf);
        do_level(l, q0, q1, k0, k1, vf);
        q0 = nq0; q1 = nq1; k0 = nk0; k1 = nk1;
#pragma unroll
        for (int i = 0; i < 4; ++i) vf[i] = nvf[i];
    }

    // ---- epilogue ----
    float extraA = 0.f;
    float yext[4] = {0.f, 0.f, 0.f, 0.f};
    if (COARSE) {
        const float* yb = yc + (size_t)z * YROWS * 64;
        const float* ab = ac + (size_t)z * YROWS;
        const int o5 = (B >> 1), o6 = 256 + (B >> 2), o7 = 384 + (B >> 3), o8 = 448 + (B >> 4);
        extraA = ab[o5] + ab[o6] + ab[o7] + ab[o8];
#pragma unroll
        for (int nt = 0; nt < 4; ++nt) {
            const int col = nt * 16 + m;
            yext[nt] = yb[o5 * 64 + col] + yb[o6 * 64 + col] + yb[o7 * 64 + col] + yb[o8 * 64 + col];
        }
    }
    float* ob = out + zf + (size_t)B * 16 * DIM;
#pragma unroll
    for (int r = 0; r < 4; ++r) {
        const float inv = 1.0f / (A[r] + extraA + 1e-8f);
#pragma unroll
        for (int nt = 0; nt < 4; ++nt)
            ob[(quad * 4 + r) * 64 + nt * 16 + m] = (Y[nt][r] + yext[nt]) * inv;
    }
}

// ---------------- coarse (levels 5..8, once per z) ----------------
// Tile tl at level l = pooled q-rows tl*16..+15, all sharing k-block tl^1.
__global__ __launch_bounds__(64) void coarse_kernel(
    const _Float16* __restrict__ qp, const _Float16* __restrict__ kp,
    const _Float16* __restrict__ vp, float* __restrict__ yc, float* __restrict__ ac) {
    const int t = threadIdx.x, m = t & 15, quad = t >> 4;
    const int u = blockIdx.x, z = blockIdx.y;
    int l, tl, co;
    if (u < 16)      { l = 5; tl = u;      co = 0;   }
    else if (u < 24) { l = 6; tl = u - 16; co = 256; }
    else if (u < 28) { l = 7; tl = u - 24; co = 384; }
    else             { l = 8; tl = u - 28; co = 448; }
    const int kb = tl ^ 1;
    const size_t zp8 = (size_t)z * ROWS_CMP * DIM;
    const size_t zpv = (size_t)z * ROWS_V * DIM;

    const uint4a* qr = (const uint4a*)(qp + zp8 + (size_t)(OFF8[l] + tl * 16 + m) * DIM);
    const v8h qf0 = __builtin_bit_cast(v8h, qr[quad]);
    const v8h qf1 = __builtin_bit_cast(v8h, qr[4 + quad]);
    const uint4a* kr = (const uint4a*)(kp + zp8 + (size_t)(OFF8[l] + kb * 16 + m) * DIM);
    const v8h kf0 = __builtin_bit_cast(v8h, kr[quad]);
    const v8h kf1 = __builtin_bit_cast(v8h, kr[4 + quad]);
    const _Float16* vb = vp + zpv + (size_t)(SEQN + OFF8[l] + kb * 16) * DIM;
    uint2 vfr[4];
#pragma unroll
    for (int nt = 0; nt < 4; ++nt)
        vfr[nt] = *(const uint2a*)(vb + (nt * 16 + m) * 16 + quad * 4);

    v4f s4 = (v4f){0.f, 0.f, 0.f, 0.f};
    s4 = __builtin_amdgcn_mfma_f32_16x16x32_f16(kf0, qf0, s4, 0, 0, 0);
    s4 = __builtin_amdgcn_mfma_f32_16x16x32_f16(kf1, qf1, s4, 0, 0, 0);
    float mx = fmaxf(fmaxf(s4[0], s4[1]), fmaxf(s4[2], s4[3]));
    mx = fmaxf(mx, __shfl_xor(mx, 16, 64));
    mx = fmaxf(mx, __shfl_xor(mx, 32, 64));
    float e0 = __expf(s4[0] - mx), e1 = __expf(s4[1] - mx);
    float e2 = __expf(s4[2] - mx), e3 = __expf(s4[3] - mx);
    float sm = e0 + e1 + e2 + e3;
    sm += __shfl_xor(sm, 16, 64);
    sm += __shfl_xor(sm, 32, 64);
    const int sl = m + (quad << 4);  // 16 distinct q-rows: l=0 pattern
    v4h pf;
    pf[0] = (_Float16)bperm(sl, e0);
    pf[1] = (_Float16)bperm(sl, e1);
    pf[2] = (_Float16)bperm(sl, e2);
    pf[3] = (_Float16)bperm(sl, e3);
    v4f Yt[4];
#pragma unroll
    for (int nt = 0; nt < 4; ++nt) {
        Yt[nt] = (v4f){0.f, 0.f, 0.f, 0.f};
        Yt[nt] = __builtin_amdgcn_mfma_f32_16x16x16f16(pf, __builtin_bit_cast(v4h, vfr[nt]),
                                                       Yt[nt], 0, 0, 0);
    }
    float Ar[4];
#pragma unroll
    for (int r = 0; r < 4; ++r) Ar[r] = bperm(quad * 4 + r, sm);

    float* yb = yc + ((size_t)z * YROWS + co + tl * 16) * 64;
#pragma unroll
    for (int r = 0; r < 4; ++r)
#pragma unroll
        for (int nt = 0; nt < 4; ++nt)
            yb[(quad * 4 + r) * 64 + nt * 16 + m] = Yt[nt][r];
    if (m == 0) {
#pragma unroll
        for (int r = 0; r < 4; ++r)
            ac[(size_t)z * YROWS + co + tl * 16 + quad * 4 + r] = Ar[r];
    }
}

extern "C" void kernel_launch(void* const* d_in, const int* in_sizes, int n_in,
                              void* d_out, int out_size, void* d_ws, size_t ws_size,
                              hipStream_t stream) {
    const float* q = (const float*)d_in[0];
    const float* k = (const float*)d_in[1];
    const float* v = (const float*)d_in[2];
    float* out = (float*)d_out;

    const size_t T8 = (size_t)NBH * ROWS_CMP * DIM * sizeof(_Float16);  // 33,423,360
    const size_t TV = (size_t)NBH * ROWS_V * DIM * sizeof(_Float16);    // 66,977,792
    const size_t YCB = (size_t)NBH * YROWS * 64 * sizeof(float);        // 3,932,160
    const size_t ACB = (size_t)NBH * YROWS * sizeof(float);             // 61,440
    char* wsp = (char*)d_ws;
    _Float16* qp = (_Float16*)wsp;
    _Float16* kp = (_Float16*)(wsp + T8);
    _Float16* vp = (_Float16*)(wsp + 2 * T8);

    pool_kernel<<<dim3(SEQN / 256, NBH, 3), 256, 0, stream>>>(q, k, v, qp, kp, vp);
    if (ws_size >= 2 * T8 + TV + YCB + ACB) {
        float* yc = (float*)(wsp + 2 * T8 + TV);
        float* ac = (float*)(wsp + 2 * T8 + TV + YCB);
        coarse_kernel<<<dim3(30, NBH), 64, 0, stream>>>(qp, kp, vp, yc, ac);
        attend_kernel<true><<<dim3(SEQN / 64, NBH), 256, 0, stream>>>(q, k, v, qp, kp, vp, yc,
                                                                      ac, out);
    } else {
        attend_kernel<false><<<dim3(SEQN / 64, NBH), 256, 0, stream>>>(q, k, v, qp, kp, vp,
                                                                       nullptr, nullptr, out);
    }
}

// Round 4
// 305.492 us; speedup vs baseline: 1.0325x; 1.0097x over previous
//
#include <hip/hip_runtime.h>

// HAttention1D: b=4,h=8,n=8192,d=64,bsz=16, levels 0..8.
// out[i] = sum_l y_l[i>>l] / (sum_l a_l[i>>l] + 1e-8); level 0: block-diagonal
// 16x16 attention; level l>=1: query block attends sibling block (B>>l)^1 on
// mean-pooled q,k (q pre-scaled d^-0.5) / sum-pooled v.
//
// R8: pool instruction diet. R7 post-mortem: pool was VMEM-issue bound (~87M
// vmem instrs: 64 scalar loads + 63 scalar 2B stores per q/k thread), not
// byte-bound. New pool uses the R6-proven mapping (thread owns 4 cols x 16
// rows): 16x float4 loads, levels 1..4 thread-local with 8B vector stores,
// levels 5..6 via shfl_xor, 7..8 via LDS. Also: fine-V fp16 was DEAD data
// (attend reads level-0 V from fp32 input) -> deleted; vp is coarse-only.
// ~25M vmem instrs (3.5x fewer), writes 137->104 MB. Attend/coarse unchanged
// except vp offset (coarse-only layout).

#define NBH 32
#define SEQN 8192
#define DIM 64
#define ROWS_CMP 8160    // coarse rows per z: 4096+2048+...+32 (levels 1..8)
#define YROWS 480        // coarse y rows per z: 256(l5)+128(l6)+64(l7)+32(l8)

typedef _Float16 v2h __attribute__((ext_vector_type(2)));
typedef _Float16 v4h __attribute__((ext_vector_type(4)));
typedef _Float16 v8h __attribute__((ext_vector_type(8)));
typedef float v4f __attribute__((ext_vector_type(4)));
typedef v4f v4fa __attribute__((may_alias));
typedef float4 float4a __attribute__((may_alias));
typedef uint4 uint4a __attribute__((may_alias));
typedef uint2 uint2a __attribute__((may_alias));
typedef unsigned int uinta __attribute__((may_alias));

// coarse level offsets (rows), OFF8[0]/[1]: level-1 starts at 0
__constant__ int OFF8[9] = {0, 0, 4096, 6144, 7168, 7680, 7936, 8064, 8128};

// ---------------- pool ----------------
// mode (blockIdx.z): 0=q (mean, *0.125), 1=k (mean), 2=v (sum, col-major
// 16-row blocks). Coarse-only output. Thread t owns cols d4..d4+3
// (d4=(t&15)*4) and rows rgrp*16..+15 (rgrp=t>>4) of a 256-row chunk.
__global__ __launch_bounds__(256) void pool_kernel(
    const float* __restrict__ q, const float* __restrict__ k, const float* __restrict__ v,
    _Float16* __restrict__ qp, _Float16* __restrict__ kp, _Float16* __restrict__ vp) {
    const int chunk = blockIdx.x, z = blockIdx.y, mode = blockIdx.z;
    const int t = threadIdx.x;
    const int d4i = t & 15, d4 = d4i * 4, rgrp = t >> 4;
    const float* __restrict__ in = (mode == 0) ? q : (mode == 1) ? k : v;
    _Float16* __restrict__ pyr = (mode == 0) ? qp : (mode == 1) ? kp : vp;
    const float fs = (mode == 0) ? 0.125f : 1.0f;   // fine-level scale (d^-0.5)
    const float sc = (mode == 2) ? 1.0f : 0.5f;     // pool scale (sum vs mean)
    const bool vlay = (mode == 2);
    const size_t zb = (size_t)z * ROWS_CMP;
    __shared__ float lds[4][64];
    const int row16 = chunk * 256 + rgrp * 16;

    v4f val[16];
    {
        const v4fa* src = (const v4fa*)(in + ((size_t)z * SEQN + row16) * DIM) + d4i;
#pragma unroll
        for (int r = 0; r < 16; ++r) val[r] = src[r * 16] * fs;
    }

    // ---- levels 1..4 (thread-local over this 16-row group) ----
#pragma unroll
    for (int l = 1; l <= 4; ++l) {
        const int nr = 16 >> l;
#pragma unroll
        for (int r = 0; r < nr; ++r) val[r] = (val[2 * r] + val[2 * r + 1]) * sc;
        const int row0 = row16 >> l;
        if (!vlay) {
            _Float16* dst = pyr + (zb + OFF8[l] + row0) * DIM + d4;
#pragma unroll
            for (int r = 0; r < nr; ++r) {
                v4h h;
#pragma unroll
                for (int i = 0; i < 4; ++i) h[i] = (_Float16)val[r][i];
                *(uint2a*)(dst + (size_t)r * DIM) = __builtin_bit_cast(uint2, h);
            }
        } else {
            const int r4 = row0 & 15;
            _Float16* base = pyr + (zb + OFF8[l] + (row0 & ~15)) * DIM + r4;
#pragma unroll
            for (int c = 0; c < 4; ++c) {
                _Float16* dc = base + (d4 + c) * 16;
                if (nr == 8) {           // r4 = (rgrp&1)*8: 16B aligned
                    v8h h;
#pragma unroll
                    for (int i = 0; i < 8; ++i) h[i] = (_Float16)val[i][c];
                    *(uint4a*)dc = __builtin_bit_cast(uint4, h);
                } else if (nr == 4) {    // r4 = (rgrp&3)*4: 8B aligned
                    v4h h;
#pragma unroll
                    for (int i = 0; i < 4; ++i) h[i] = (_Float16)val[i][c];
                    *(uint2a*)dc = __builtin_bit_cast(uint2, h);
                } else if (nr == 2) {    // r4 = (rgrp&7)*2: 4B aligned
                    v2h h;
                    h[0] = (_Float16)val[0][c];
                    h[1] = (_Float16)val[1][c];
                    *(uinta*)dc = __builtin_bit_cast(unsigned int, h);
                } else {                 // nr == 1 (level 4), r4 = rgrp
                    *dc = (_Float16)val[0][c];
                }
            }
        }
    }

    // ---- level 5 (shfl_xor 16: pairs of rgrp) ----
    v4f v5, v6;
#pragma unroll
    for (int c = 0; c < 4; ++c) v5[c] = __shfl_xor(val[0][c], 16, 64);
    v5 = (val[0] + v5) * sc;
    const int row5 = row16 >> 5;
    if ((rgrp & 1) == 0) {
        if (!vlay) {
            v4h h;
#pragma unroll
            for (int i = 0; i < 4; ++i) h[i] = (_Float16)v5[i];
            *(uint2a*)(pyr + (zb + OFF8[5] + row5) * DIM + d4) = __builtin_bit_cast(uint2, h);
        } else {
            const int r4 = row5 & 15;
            _Float16* base = pyr + (zb + OFF8[5] + (row5 & ~15)) * DIM + r4;
#pragma unroll
            for (int c = 0; c < 4; ++c) base[(d4 + c) * 16] = (_Float16)v5[c];
        }
    }
    // ---- level 6 (shfl_xor 32) ----
#pragma unroll
    for (int c = 0; c < 4; ++c) v6[c] = __shfl_xor(v5[c], 32, 64);
    v6 = (v5 + v6) * sc;
    const int row6 = row16 >> 6;
    if ((rgrp & 3) == 0) {
        if (!vlay) {
            v4h h;
#pragma unroll
            for (int i = 0; i < 4; ++i) h[i] = (_Float16)v6[i];
            *(uint2a*)(pyr + (zb + OFF8[6] + row6) * DIM + d4) = __builtin_bit_cast(uint2, h);
        } else {
            const int r4 = row6 & 15;
            _Float16* base = pyr + (zb + OFF8[6] + (row6 & ~15)) * DIM + r4;
#pragma unroll
            for (int c = 0; c < 4; ++c) base[(d4 + c) * 16] = (_Float16)v6[c];
        }
#pragma unroll
        for (int c = 0; c < 4; ++c) lds[rgrp >> 2][d4 + c] = v6[c];
    }
    __syncthreads();
    // ---- levels 7,8 (cross-wave via LDS) ----
    if (t < 64) {
        const float l7a = (lds[0][t] + lds[1][t]) * sc;
        const float l7b = (lds[2][t] + lds[3][t]) * sc;
        const float l8v = (l7a + l7b) * sc;
        const int a7 = chunk * 2;
        if (!vlay) {
            _Float16* d7 = pyr + (zb + OFF8[7] + a7) * DIM + t;
            d7[0] = (_Float16)l7a;
            d7[DIM] = (_Float16)l7b;
            pyr[(zb + OFF8[8] + chunk) * DIM + t] = (_Float16)l8v;
        } else {
            v2h h;
            h[0] = (_Float16)l7a;
            h[1] = (_Float16)l7b;
            *(uinta*)(pyr + (zb + OFF8[7] + (a7 & ~15)) * DIM + t * 16 + (a7 & 15)) =
                __builtin_bit_cast(unsigned int, h);
            pyr[(zb + OFF8[8] + (chunk & ~15)) * DIM + t * 16 + (chunk & 15)] =
                (_Float16)l8v;
        }
    }
}

// ---------------- attend ----------------
__device__ __forceinline__ float bperm(int lane, float x) {
    return __int_as_float(__builtin_amdgcn_ds_bpermute(lane << 2, __float_as_int(x)));
}

// 256 threads = 4 independent waves; wave w handles output block B = bx*4+w.
// No LDS. Level 0: Q/K fragments straight from fp32 inputs (2x float4 + cvt,
// rounding identical to pooled-fp16 path), V from fp32 input (col gather).
// Levels 1..4 from coarse pyramid; 5..8 added in epilogue from coarse kernel.
template <bool COARSE>
__global__ __launch_bounds__(256) void attend_kernel(
    const float* __restrict__ qg, const float* __restrict__ kg, const float* __restrict__ vg,
    const _Float16* __restrict__ qp, const _Float16* __restrict__ kp,
    const _Float16* __restrict__ vp, const float* __restrict__ yc,
    const float* __restrict__ ac, float* __restrict__ out) {
    const int tid = threadIdx.x;
    const int t = tid & 63, w = tid >> 6;
    const int m = t & 15, quad = t >> 4;
    const int B = blockIdx.x * 4 + w;
    const int z = blockIdx.y;
    const size_t zp8 = (size_t)z * ROWS_CMP * DIM;
    const size_t zf = (size_t)z * SEQN * DIM;
    constexpr int LMAX = COARSE ? 4 : 8;

    v4f Y[4];
    float A[4];
#pragma unroll
    for (int nt = 0; nt < 4; ++nt) Y[nt] = (v4f){0.f, 0.f, 0.f, 0.f};
#pragma unroll
    for (int r = 0; r < 4; ++r) A[r] = 0.f;

    auto issue = [&](int l, v8h& qf0, v8h& qf1, v8h& kf0, v8h& kf1, uint2 (&vfr)[4]) {
        if (l == 0) {
            const float4a* qr = (const float4a*)(qg + zf + (size_t)(B * 16 + m) * DIM + quad * 8);
            const float4 qa0 = qr[0], qa1 = qr[1], qb0 = qr[8], qb1 = qr[9];
            const float4a* kr = (const float4a*)(kg + zf + (size_t)(B * 16 + m) * DIM + quad * 8);
            const float4 ka0 = kr[0], ka1 = kr[1], kb0 = kr[8], kb1 = kr[9];
            v8h h;
            h[0] = (_Float16)(qa0.x * 0.125f); h[1] = (_Float16)(qa0.y * 0.125f);
            h[2] = (_Float16)(qa0.z * 0.125f); h[3] = (_Float16)(qa0.w * 0.125f);
            h[4] = (_Float16)(qa1.x * 0.125f); h[5] = (_Float16)(qa1.y * 0.125f);
            h[6] = (_Float16)(qa1.z * 0.125f); h[7] = (_Float16)(qa1.w * 0.125f);
            qf0 = h;
            h[0] = (_Float16)(qb0.x * 0.125f); h[1] = (_Float16)(qb0.y * 0.125f);
            h[2] = (_Float16)(qb0.z * 0.125f); h[3] = (_Float16)(qb0.w * 0.125f);
            h[4] = (_Float16)(qb1.x * 0.125f); h[5] = (_Float16)(qb1.y * 0.125f);
            h[6] = (_Float16)(qb1.z * 0.125f); h[7] = (_Float16)(qb1.w * 0.125f);
            qf1 = h;
            h[0] = (_Float16)ka0.x; h[1] = (_Float16)ka0.y;
            h[2] = (_Float16)ka0.z; h[3] = (_Float16)ka0.w;
            h[4] = (_Float16)ka1.x; h[5] = (_Float16)ka1.y;
            h[6] = (_Float16)ka1.z; h[7] = (_Float16)ka1.w;
            kf0 = h;
            h[0] = (_Float16)kb0.x; h[1] = (_Float16)kb0.y;
            h[2] = (_Float16)kb0.z; h[3] = (_Float16)kb0.w;
            h[4] = (_Float16)kb1.x; h[5] = (_Float16)kb1.y;
            h[6] = (_Float16)kb1.z; h[7] = (_Float16)kb1.w;
            kf1 = h;
            const float* vb = vg + zf + (size_t)(B * 16) * DIM;
#pragma unroll
            for (int nt = 0; nt < 4; ++nt) {
                v4h hv;
#pragma unroll
                for (int i = 0; i < 4; ++i)
                    hv[i] = (_Float16)vb[(quad * 4 + i) * DIM + nt * 16 + m];
                vfr[nt] = __builtin_bit_cast(uint2, hv);
            }
        } else {
            const int c = (l <= 4) ? (16 >> l) : 1;
            const int qrow0 = (B * 16) >> l;
            const int kb = (B >> l) ^ 1;
            const int qm = (m < c) ? m : (c - 1);  // clamp: duplicate valid rows
            const uint4a* qr = (const uint4a*)(qp + zp8 + (size_t)(OFF8[l] + qrow0 + qm) * DIM);
            qf0 = __builtin_bit_cast(v8h, qr[quad]);
            qf1 = __builtin_bit_cast(v8h, qr[4 + quad]);
            const uint4a* kr = (const uint4a*)(kp + zp8 + (size_t)(OFF8[l] + kb * 16 + m) * DIM);
            kf0 = __builtin_bit_cast(v8h, kr[quad]);
            kf1 = __builtin_bit_cast(v8h, kr[4 + quad]);
            const _Float16* vb = vp + zp8 + (size_t)(OFF8[l] + kb * 16) * DIM;
#pragma unroll
            for (int nt = 0; nt < 4; ++nt)
                vfr[nt] = *(const uint2a*)(vb + (nt * 16 + m) * 16 + quad * 4);
        }
    };

    auto do_level = [&](int l, v8h qf0, v8h qf1, v8h kf0, v8h kf1, const uint2 (&vfr)[4]) {
        // S^T[j][m] = sum_d K[j][d]*Qs[m][d]; A-frag rows = K, B-frag rows = Q.
        v4f s4 = (v4f){0.f, 0.f, 0.f, 0.f};
        s4 = __builtin_amdgcn_mfma_f32_16x16x32_f16(kf0, qf0, s4, 0, 0, 0);
        s4 = __builtin_amdgcn_mfma_f32_16x16x32_f16(kf1, qf1, s4, 0, 0, 0);
        float mx = fmaxf(fmaxf(s4[0], s4[1]), fmaxf(s4[2], s4[3]));
        mx = fmaxf(mx, __shfl_xor(mx, 16, 64));
        mx = fmaxf(mx, __shfl_xor(mx, 32, 64));
        float e0 = __expf(s4[0] - mx), e1 = __expf(s4[1] - mx);
        float e2 = __expf(s4[2] - mx), e3 = __expf(s4[3] - mx);
        float sm = e0 + e1 + e2 + e3;
        sm += __shfl_xor(sm, 16, 64);
        sm += __shfl_xor(sm, 32, 64);
        const int sl = (m >> l) + (quad << 4);
        v4h pf;
        pf[0] = (_Float16)bperm(sl, e0);
        pf[1] = (_Float16)bperm(sl, e1);
        pf[2] = (_Float16)bperm(sl, e2);
        pf[3] = (_Float16)bperm(sl, e3);
#pragma unroll
        for (int nt = 0; nt < 4; ++nt)
            Y[nt] = __builtin_amdgcn_mfma_f32_16x16x16f16(pf, __builtin_bit_cast(v4h, vfr[nt]),
                                                          Y[nt], 0, 0, 0);
#pragma unroll
        for (int r = 0; r < 4; ++r) A[r] += bperm((quad * 4 + r) >> l, sm);
    };

    v8h q0{}, q1{}, k0{}, k1{};
    uint2 vf[4] = {};
    issue(0, q0, q1, k0, k1, vf);
#pragma unroll
    for (int l = 0; l <= LMAX; ++l) {
        v8h nq0{}, nq1{}, nk0{}, nk1{};
        uint2 nvf[4] = {};
        if (l < LMAX) issue(l + 1, nq0, nq1, nk0, nk1, nvf);
        do_level(l, q0, q1, k0, k1, vf);
        q0 = nq0; q1 = nq1; k0 = nk0; k1 = nk1;
#pragma unroll
        for (int i = 0; i < 4; ++i) vf[i] = nvf[i];
    }

    // ---- epilogue ----
    float extraA = 0.f;
    float yext[4] = {0.f, 0.f, 0.f, 0.f};
    if (COARSE) {
        const float* yb = yc + (size_t)z * YROWS * 64;
        const float* ab = ac + (size_t)z * YROWS;
        const int o5 = (B >> 1), o6 = 256 + (B >> 2), o7 = 384 + (B >> 3), o8 = 448 + (B >> 4);
        extraA = ab[o5] + ab[o6] + ab[o7] + ab[o8];
#pragma unroll
        for (int nt = 0; nt < 4; ++nt) {
            const int col = nt * 16 + m;
            yext[nt] = yb[o5 * 64 + col] + yb[o6 * 64 + col] + yb[o7 * 64 + col] + yb[o8 * 64 + col];
        }
    }
    float* ob = out + zf + (size_t)B * 16 * DIM;
#pragma unroll
    for (int r = 0; r < 4; ++r) {
        const float inv = 1.0f / (A[r] + extraA + 1e-8f);
#pragma unroll
        for (int nt = 0; nt < 4; ++nt)
            ob[(quad * 4 + r) * 64 + nt * 16 + m] = (Y[nt][r] + yext[nt]) * inv;
    }
}

// ---------------- coarse (levels 5..8, once per z) ----------------
// Tile tl at level l = pooled q-rows tl*16..+15, all sharing k-block tl^1.
__global__ __launch_bounds__(64) void coarse_kernel(
    const _Float16* __restrict__ qp, const _Float16* __restrict__ kp,
    const _Float16* __restrict__ vp, float* __restrict__ yc, float* __restrict__ ac) {
    const int t = threadIdx.x, m = t & 15, quad = t >> 4;
    const int u = blockIdx.x, z = blockIdx.y;
    int l, tl, co;
    if (u < 16)      { l = 5; tl = u;      co = 0;   }
    else if (u < 24) { l = 6; tl = u - 16; co = 256; }
    else if (u < 28) { l = 7; tl = u - 24; co = 384; }
    else             { l = 8; tl = u - 28; co = 448; }
    const int kb = tl ^ 1;
    const size_t zp8 = (size_t)z * ROWS_CMP * DIM;

    const uint4a* qr = (const uint4a*)(qp + zp8 + (size_t)(OFF8[l] + tl * 16 + m) * DIM);
    const v8h qf0 = __builtin_bit_cast(v8h, qr[quad]);
    const v8h qf1 = __builtin_bit_cast(v8h, qr[4 + quad]);
    const uint4a* kr = (const uint4a*)(kp + zp8 + (size_t)(OFF8[l] + kb * 16 + m) * DIM);
    const v8h kf0 = __builtin_bit_cast(v8h, kr[quad]);
    const v8h kf1 = __builtin_bit_cast(v8h, kr[4 + quad]);
    const _Float16* vb = vp + zp8 + (size_t)(OFF8[l] + kb * 16) * DIM;
    uint2 vfr[4];
#pragma unroll
    for (int nt = 0; nt < 4; ++nt)
        vfr[nt] = *(const uint2a*)(vb + (nt * 16 + m) * 16 + quad * 4);

    v4f s4 = (v4f){0.f, 0.f, 0.f, 0.f};
    s4 = __builtin_amdgcn_mfma_f32_16x16x32_f16(kf0, qf0, s4, 0, 0, 0);
    s4 = __builtin_amdgcn_mfma_f32_16x16x32_f16(kf1, qf1, s4, 0, 0, 0);
    float mx = fmaxf(fmaxf(s4[0], s4[1]), fmaxf(s4[2], s4[3]));
    mx = fmaxf(mx, __shfl_xor(mx, 16, 64));
    mx = fmaxf(mx, __shfl_xor(mx, 32, 64));
    float e0 = __expf(s4[0] - mx), e1 = __expf(s4[1] - mx);
    float e2 = __expf(s4[2] - mx), e3 = __expf(s4[3] - mx);
    float sm = e0 + e1 + e2 + e3;
    sm += __shfl_xor(sm, 16, 64);
    sm += __shfl_xor(sm, 32, 64);
    const int sl = m + (quad << 4);  // 16 distinct q-rows: l=0 pattern
    v4h pf;
    pf[0] = (_Float16)bperm(sl, e0);
    pf[1] = (_Float16)bperm(sl, e1);
    pf[2] = (_Float16)bperm(sl, e2);
    pf[3] = (_Float16)bperm(sl, e3);
    v4f Yt[4];
#pragma unroll
    for (int nt = 0; nt < 4; ++nt) {
        Yt[nt] = (v4f){0.f, 0.f, 0.f, 0.f};
        Yt[nt] = __builtin_amdgcn_mfma_f32_16x16x16f16(pf, __builtin_bit_cast(v4h, vfr[nt]),
                                                       Yt[nt], 0, 0, 0);
    }
    float Ar[4];
#pragma unroll
    for (int r = 0; r < 4; ++r) Ar[r] = bperm(quad * 4 + r, sm);

    float* yb = yc + ((size_t)z * YROWS + co + tl * 16) * 64;
#pragma unroll
    for (int r = 0; r < 4; ++r)
#pragma unroll
        for (int nt = 0; nt < 4; ++nt)
            yb[(quad * 4 + r) * 64 + nt * 16 + m] = Yt[nt][r];
    if (m == 0) {
#pragma unroll
        for (int r = 0; r < 4; ++r)
            ac[(size_t)z * YROWS + co + tl * 16 + quad * 4 + r] = Ar[r];
    }
}

extern "C" void kernel_launch(void* const* d_in, const int* in_sizes, int n_in,
                              void* d_out, int out_size, void* d_ws, size_t ws_size,
                              hipStream_t stream) {
    const float* q = (const float*)d_in[0];
    const float* k = (const float*)d_in[1];
    const float* v = (const float*)d_in[2];
    float* out = (float*)d_out;

    const size_t T8 = (size_t)NBH * ROWS_CMP * DIM * sizeof(_Float16);  // 33,423,360
    const size_t YCB = (size_t)NBH * YROWS * 64 * sizeof(float);        // 3,932,160
    const size_t ACB = (size_t)NBH * YROWS * sizeof(float);             // 61,440
    char* wsp = (char*)d_ws;
    _Float16* qp = (_Float16*)wsp;
    _Float16* kp = (_Float16*)(wsp + T8);
    _Float16* vp = (_Float16*)(wsp + 2 * T8);

    pool_kernel<<<dim3(SEQN / 256, NBH, 3), 256, 0, stream>>>(q, k, v, qp, kp, vp);
    if (ws_size >= 3 * T8 + YCB + ACB) {
        float* yc = (float*)(wsp + 3 * T8);
        float* ac = (float*)(wsp + 3 * T8 + YCB);
        coarse_kernel<<<dim3(30, NBH), 64, 0, stream>>>(qp, kp, vp, yc, ac);
        attend_kernel<true><<<dim3(SEQN / 64, NBH), 256, 0, stream>>>(q, k, v, qp, kp, vp, yc,
                                                                      ac, out);
    } else {
        attend_kernel<false><<<dim3(SEQN / 64, NBH), 256, 0, stream>>>(q, k, v, qp, kp, vp,
                                                                       nullptr, nullptr, out);
    }
}

// Round 5
// 302.381 us; speedup vs baseline: 1.0431x; 1.0103x over previous
//
#include <hip/hip_runtime.h>

// HAttention1D: b=4,h=8,n=8192,d=64,bsz=16, levels 0..8.
// out[i] = sum_l y_l[i>>l] / (sum_l a_l[i>>l] + 1e-8); level 0: block-diagonal
// 16x16 attention; level l>=1: query block attends sibling block (B>>l)^1 on
// mean-pooled q,k (q pre-scaled d^-0.5) / sum-pooled v.
//
// R9: pool load-pipelining experiment. R8 post-mortem: VGPR_Count=36 with
// val[16] (needs 64 regs) proves the compiler consumed loads pairwise ->
// only ~2-4 loads in flight, latency-serialized, one 64KB chunk per WG.
// New pool: each WG streams NC=4 chunks with explicit double-buffer prefetch
// (valA/valB, unroll-2, static indexing) so 16 float4 loads are always in
// flight; per-chunk __syncthreads removed (barrier drains vmcnt) -- level-6
// partials for all chunks parked in LDS, ONE barrier + tail at WG end.
// Math/layout/stores bit-identical to R8. Attend/coarse unchanged.

#define NBH 32
#define SEQN 8192
#define DIM 64
#define ROWS_CMP 8160    // coarse rows per z: 4096+2048+...+32 (levels 1..8)
#define YROWS 480        // coarse y rows per z: 256(l5)+128(l6)+64(l7)+32(l8)
#define NC 4             // chunks per pool WG (grid-stride depth)

typedef _Float16 v2h __attribute__((ext_vector_type(2)));
typedef _Float16 v4h __attribute__((ext_vector_type(4)));
typedef _Float16 v8h __attribute__((ext_vector_type(8)));
typedef float v4f __attribute__((ext_vector_type(4)));
typedef v4f v4fa __attribute__((may_alias));
typedef float4 float4a __attribute__((may_alias));
typedef uint4 uint4a __attribute__((may_alias));
typedef uint2 uint2a __attribute__((may_alias));
typedef unsigned int uinta __attribute__((may_alias));

// coarse level offsets (rows), OFF8[0]/[1]: level-1 starts at 0
__constant__ int OFF8[9] = {0, 0, 4096, 6144, 7168, 7680, 7936, 8064, 8128};

// ---------------- pool ----------------
// mode (blockIdx.z): 0=q (mean, *0.125), 1=k (mean), 2=v (sum, col-major
// 16-row blocks). Coarse-only output. Thread t owns cols d4..d4+3
// (d4=(t&15)*4) and rows rgrp*16..+15 of each 256-row chunk; WG covers
// chunks c0..c0+NC-1 with double-buffered prefetch.
__global__ __launch_bounds__(256, 3) void pool_kernel(
    const float* __restrict__ q, const float* __restrict__ k, const float* __restrict__ v,
    _Float16* __restrict__ qp, _Float16* __restrict__ kp, _Float16* __restrict__ vp) {
    const int gx = blockIdx.x, z = blockIdx.y, mode = blockIdx.z;
    const int t = threadIdx.x;
    const int d4i = t & 15, d4 = d4i * 4, rgrp = t >> 4;
    const float* __restrict__ in = (mode == 0) ? q : (mode == 1) ? k : v;
    _Float16* __restrict__ pyr = (mode == 0) ? qp : (mode == 1) ? kp : vp;
    const float fs = (mode == 0) ? 0.125f : 1.0f;   // fine-level scale (d^-0.5)
    const float sc = (mode == 2) ? 1.0f : 0.5f;     // pool scale (sum vs mean)
    const bool vlay = (mode == 2);
    const size_t zb = (size_t)z * ROWS_CMP;
    __shared__ float lds[NC][4][64];                // level-6 partials per chunk
    const int c0 = gx * NC;

    auto loadchunk = [&](v4f (&val)[16], int chunk) {
        const int row16 = chunk * 256 + rgrp * 16;
        const v4fa* src = (const v4fa*)(in + ((size_t)z * SEQN + row16) * DIM) + d4i;
#pragma unroll
        for (int r = 0; r < 16; ++r) val[r] = src[r * 16] * fs;
    };

    auto process = [&](v4f (&val)[16], int chunk, float (&lrow)[4][64]) {
        const int row16 = chunk * 256 + rgrp * 16;
        // ---- levels 1..4 (thread-local over this 16-row group) ----
#pragma unroll
        for (int l = 1; l <= 4; ++l) {
            const int nr = 16 >> l;
#pragma unroll
            for (int r = 0; r < nr; ++r) val[r] = (val[2 * r] + val[2 * r + 1]) * sc;
            const int row0 = row16 >> l;
            if (!vlay) {
                _Float16* dst = pyr + (zb + OFF8[l] + row0) * DIM + d4;
#pragma unroll
                for (int r = 0; r < nr; ++r) {
                    v4h h;
#pragma unroll
                    for (int i = 0; i < 4; ++i) h[i] = (_Float16)val[r][i];
                    *(uint2a*)(dst + (size_t)r * DIM) = __builtin_bit_cast(uint2, h);
                }
            } else {
                const int r4 = row0 & 15;
                _Float16* base = pyr + (zb + OFF8[l] + (row0 & ~15)) * DIM + r4;
#pragma unroll
                for (int c = 0; c < 4; ++c) {
                    _Float16* dc = base + (d4 + c) * 16;
                    if (nr == 8) {           // r4 = (rgrp&1)*8: 16B aligned
                        v8h h;
#pragma unroll
                        for (int i = 0; i < 8; ++i) h[i] = (_Float16)val[i][c];
                        *(uint4a*)dc = __builtin_bit_cast(uint4, h);
                    } else if (nr == 4) {    // r4 = (rgrp&3)*4: 8B aligned
                        v4h h;
#pragma unroll
                        for (int i = 0; i < 4; ++i) h[i] = (_Float16)val[i][c];
                        *(uint2a*)dc = __builtin_bit_cast(uint2, h);
                    } else if (nr == 2) {    // r4 = (rgrp&7)*2: 4B aligned
                        v2h h;
                        h[0] = (_Float16)val[0][c];
                        h[1] = (_Float16)val[1][c];
                        *(uinta*)dc = __builtin_bit_cast(unsigned int, h);
                    } else {                 // nr == 1 (level 4), r4 = rgrp
                        *dc = (_Float16)val[0][c];
                    }
                }
            }
        }
        // ---- level 5 (shfl_xor 16: pairs of rgrp) ----
        v4f v5, v6;
#pragma unroll
        for (int c = 0; c < 4; ++c) v5[c] = __shfl_xor(val[0][c], 16, 64);
        v5 = (val[0] + v5) * sc;
        const int row5 = row16 >> 5;
        if ((rgrp & 1) == 0) {
            if (!vlay) {
                v4h h;
#pragma unroll
                for (int i = 0; i < 4; ++i) h[i] = (_Float16)v5[i];
                *(uint2a*)(pyr + (zb + OFF8[5] + row5) * DIM + d4) = __builtin_bit_cast(uint2, h);
            } else {
                const int r4 = row5 & 15;
                _Float16* base = pyr + (zb + OFF8[5] + (row5 & ~15)) * DIM + r4;
#pragma unroll
                for (int c = 0; c < 4; ++c) base[(d4 + c) * 16] = (_Float16)v5[c];
            }
        }
        // ---- level 6 (shfl_xor 32) ----
#pragma unroll
        for (int c = 0; c < 4; ++c) v6[c] = __shfl_xor(v5[c], 32, 64);
        v6 = (v5 + v6) * sc;
        const int row6 = row16 >> 6;
        if ((rgrp & 3) == 0) {
            if (!vlay) {
                v4h h;
#pragma unroll
                for (int i = 0; i < 4; ++i) h[i] = (_Float16)v6[i];
                *(uint2a*)(pyr + (zb + OFF8[6] + row6) * DIM + d4) = __builtin_bit_cast(uint2, h);
            } else {
                const int r4 = row6 & 15;
                _Float16* base = pyr + (zb + OFF8[6] + (row6 & ~15)) * DIM + r4;
#pragma unroll
                for (int c = 0; c < 4; ++c) base[(d4 + c) * 16] = (_Float16)v6[c];
            }
#pragma unroll
            for (int c = 0; c < 4; ++c) lrow[rgrp >> 2][d4 + c] = v6[c];
        }
    };

    // ---- streamed chunks with double-buffer prefetch (no barriers inside) ----
    v4f valA[16], valB[16];
    loadchunk(valA, c0);
#pragma unroll
    for (int i = 0; i < NC; i += 2) {
        loadchunk(valB, c0 + i + 1);
        process(valA, c0 + i, lds[i]);
        if (i + 2 < NC) loadchunk(valA, c0 + i + 2);
        process(valB, c0 + i + 1, lds[i + 1]);
    }

    // ---- levels 7,8 (one barrier, tail over all NC chunks) ----
    __syncthreads();
    if (t < 64) {
#pragma unroll
        for (int i = 0; i < NC; ++i) {
            const int chunk = c0 + i;
            const float l7a = (lds[i][0][t] + lds[i][1][t]) * sc;
            const float l7b = (lds[i][2][t] + lds[i][3][t]) * sc;
            const float l8v = (l7a + l7b) * sc;
            const int a7 = chunk * 2;
            if (!vlay) {
                _Float16* d7 = pyr + (zb + OFF8[7] + a7) * DIM + t;
                d7[0] = (_Float16)l7a;
                d7[DIM] = (_Float16)l7b;
                pyr[(zb + OFF8[8] + chunk) * DIM + t] = (_Float16)l8v;
            } else {
                v2h h;
                h[0] = (_Float16)l7a;
                h[1] = (_Float16)l7b;
                *(uinta*)(pyr + (zb + OFF8[7] + (a7 & ~15)) * DIM + t * 16 + (a7 & 15)) =
                    __builtin_bit_cast(unsigned int, h);
                pyr[(zb + OFF8[8] + (chunk & ~15)) * DIM + t * 16 + (chunk & 15)] =
                    (_Float16)l8v;
            }
        }
    }
}

// ---------------- attend ----------------
__device__ __forceinline__ float bperm(int lane, float x) {
    return __int_as_float(__builtin_amdgcn_ds_bpermute(lane << 2, __float_as_int(x)));
}

// 256 threads = 4 independent waves; wave w handles output block B = bx*4+w.
// No LDS. Level 0: Q/K fragments straight from fp32 inputs (2x float4 + cvt,
// rounding identical to pooled-fp16 path), V from fp32 input (col gather).
// Levels 1..4 from coarse pyramid; 5..8 added in epilogue from coarse kernel.
template <bool COARSE>
__global__ __launch_bounds__(256) void attend_kernel(
    const float* __restrict__ qg, const float* __restrict__ kg, const float* __restrict__ vg,
    const _Float16* __restrict__ qp, const _Float16* __restrict__ kp,
    const _Float16* __restrict__ vp, const float* __restrict__ yc,
    const float* __restrict__ ac, float* __restrict__ out) {
    const int tid = threadIdx.x;
    const int t = tid & 63, w = tid >> 6;
    const int m = t & 15, quad = t >> 4;
    const int B = blockIdx.x * 4 + w;
    const int z = blockIdx.y;
    const size_t zp8 = (size_t)z * ROWS_CMP * DIM;
    const size_t zf = (size_t)z * SEQN * DIM;
    constexpr int LMAX = COARSE ? 4 : 8;

    v4f Y[4];
    float A[4];
#pragma unroll
    for (int nt = 0; nt < 4; ++nt) Y[nt] = (v4f){0.f, 0.f, 0.f, 0.f};
#pragma unroll
    for (int r = 0; r < 4; ++r) A[r] = 0.f;

    auto issue = [&](int l, v8h& qf0, v8h& qf1, v8h& kf0, v8h& kf1, uint2 (&vfr)[4]) {
        if (l == 0) {
            const float4a* qr = (const float4a*)(qg + zf + (size_t)(B * 16 + m) * DIM + quad * 8);
            const float4 qa0 = qr[0], qa1 = qr[1], qb0 = qr[8], qb1 = qr[9];
            const float4a* kr = (const float4a*)(kg + zf + (size_t)(B * 16 + m) * DIM + quad * 8);
            const float4 ka0 = kr[0], ka1 = kr[1], kb0 = kr[8], kb1 = kr[9];
            v8h h;
            h[0] = (_Float16)(qa0.x * 0.125f); h[1] = (_Float16)(qa0.y * 0.125f);
            h[2] = (_Float16)(qa0.z * 0.125f); h[3] = (_Float16)(qa0.w * 0.125f);
            h[4] = (_Float16)(qa1.x * 0.125f); h[5] = (_Float16)(qa1.y * 0.125f);
            h[6] = (_Float16)(qa1.z * 0.125f); h[7] = (_Float16)(qa1.w * 0.125f);
            qf0 = h;
            h[0] = (_Float16)(qb0.x * 0.125f); h[1] = (_Float16)(qb0.y * 0.125f);
            h[2] = (_Float16)(qb0.z * 0.125f); h[3] = (_Float16)(qb0.w * 0.125f);
            h[4] = (_Float16)(qb1.x * 0.125f); h[5] = (_Float16)(qb1.y * 0.125f);
            h[6] = (_Float16)(qb1.z * 0.125f); h[7] = (_Float16)(qb1.w * 0.125f);
            qf1 = h;
            h[0] = (_Float16)ka0.x; h[1] = (_Float16)ka0.y;
            h[2] = (_Float16)ka0.z; h[3] = (_Float16)ka0.w;
            h[4] = (_Float16)ka1.x; h[5] = (_Float16)ka1.y;
            h[6] = (_Float16)ka1.z; h[7] = (_Float16)ka1.w;
            kf0 = h;
            h[0] = (_Float16)kb0.x; h[1] = (_Float16)kb0.y;
            h[2] = (_Float16)kb0.z; h[3] = (_Float16)kb0.w;
            h[4] = (_Float16)kb1.x; h[5] = (_Float16)kb1.y;
            h[6] = (_Float16)kb1.z; h[7] = (_Float16)kb1.w;
            kf1 = h;
            const float* vb = vg + zf + (size_t)(B * 16) * DIM;
#pragma unroll
            for (int nt = 0; nt < 4; ++nt) {
                v4h hv;
#pragma unroll
                for (int i = 0; i < 4; ++i)
                    hv[i] = (_Float16)vb[(quad * 4 + i) * DIM + nt * 16 + m];
                vfr[nt] = __builtin_bit_cast(uint2, hv);
            }
        } else {
            const int c = (l <= 4) ? (16 >> l) : 1;
            const int qrow0 = (B * 16) >> l;
            const int kb = (B >> l) ^ 1;
            const int qm = (m < c) ? m : (c - 1);  // clamp: duplicate valid rows
            const uint4a* qr = (const uint4a*)(qp + zp8 + (size_t)(OFF8[l] + qrow0 + qm) * DIM);
            qf0 = __builtin_bit_cast(v8h, qr[quad]);
            qf1 = __builtin_bit_cast(v8h, qr[4 + quad]);
            const uint4a* kr = (const uint4a*)(kp + zp8 + (size_t)(OFF8[l] + kb * 16 + m) * DIM);
            kf0 = __builtin_bit_cast(v8h, kr[quad]);
            kf1 = __builtin_bit_cast(v8h, kr[4 + quad]);
            const _Float16* vb = vp + zp8 + (size_t)(OFF8[l] + kb * 16) * DIM;
#pragma unroll
            for (int nt = 0; nt < 4; ++nt)
                vfr[nt] = *(const uint2a*)(vb + (nt * 16 + m) * 16 + quad * 4);
        }
    };

    auto do_level = [&](int l, v8h qf0, v8h qf1, v8h kf0, v8h kf1, const uint2 (&vfr)[4]) {
        // S^T[j][m] = sum_d K[j][d]*Qs[m][d]; A-frag rows = K, B-frag rows = Q.
        v4f s4 = (v4f){0.f, 0.f, 0.f, 0.f};
        s4 = __builtin_amdgcn_mfma_f32_16x16x32_f16(kf0, qf0, s4, 0, 0, 0);
        s4 = __builtin_amdgcn_mfma_f32_16x16x32_f16(kf1, qf1, s4, 0, 0, 0);
        float mx = fmaxf(fmaxf(s4[0], s4[1]), fmaxf(s4[2], s4[3]));
        mx = fmaxf(mx, __shfl_xor(mx, 16, 64));
        mx = fmaxf(mx, __shfl_xor(mx, 32, 64));
        float e0 = __expf(s4[0] - mx), e1 = __expf(s4[1] - mx);
        float e2 = __expf(s4[2] - mx), e3 = __expf(s4[3] - mx);
        float sm = e0 + e1 + e2 + e3;
        sm += __shfl_xor(sm, 16, 64);
        sm += __shfl_xor(sm, 32, 64);
        const int sl = (m >> l) + (quad << 4);
        v4h pf;
        pf[0] = (_Float16)bperm(sl, e0);
        pf[1] = (_Float16)bperm(sl, e1);
        pf[2] = (_Float16)bperm(sl, e2);
        pf[3] = (_Float16)bperm(sl, e3);
#pragma unroll
        for (int nt = 0; nt < 4; ++nt)
            Y[nt] = __builtin_amdgcn_mfma_f32_16x16x16f16(pf, __builtin_bit_cast(v4h, vfr[nt]),
                                                          Y[nt], 0, 0, 0);
#pragma unroll
        for (int r = 0; r < 4; ++r) A[r] += bperm((quad * 4 + r) >> l, sm);
    };

    v8h q0{}, q1{}, k0{}, k1{};
    uint2 vf[4] = {};
    issue(0, q0, q1, k0, k1, vf);
#pragma unroll
    for (int l = 0; l <= LMAX; ++l) {
        v8h nq0{}, nq1{}, nk0{}, nk1{};
        uint2 nvf[4] = {};
        if (l < LMAX) issue(l + 1, nq0, nq1, nk0, nk1, nvf);
        do_level(l, q0, q1, k0, k1, vf);
        q0 = nq0; q1 = nq1; k0 = nk0; k1 = nk1;
#pragma unroll
        for (int i = 0; i < 4; ++i) vf[i] = nvf[i];
    }

    // ---- epilogue ----
    float extraA = 0.f;
    float yext[4] = {0.f, 0.f, 0.f, 0.f};
    if (COARSE) {
        const float* yb = yc + (size_t)z * YROWS * 64;
        const float* ab = ac + (size_t)z * YROWS;
        const int o5 = (B >> 1), o6 = 256 + (B >> 2), o7 = 384 + (B >> 3), o8 = 448 + (B >> 4);
        extraA = ab[o5] + ab[o6] + ab[o7] + ab[o8];
#pragma unroll
        for (int nt = 0; nt < 4; ++nt) {
            const int col = nt * 16 + m;
            yext[nt] = yb[o5 * 64 + col] + yb[o6 * 64 + col] + yb[o7 * 64 + col] + yb[o8 * 64 + col];
        }
    }
    float* ob = out + zf + (size_t)B * 16 * DIM;
#pragma unroll
    for (int r = 0; r < 4; ++r) {
        const float inv = 1.0f / (A[r] + extraA + 1e-8f);
#pragma unroll
        for (int nt = 0; nt < 4; ++nt)
            ob[(quad * 4 + r) * 64 + nt * 16 + m] = (Y[nt][r] + yext[nt]) * inv;
    }
}

// ---------------- coarse (levels 5..8, once per z) ----------------
// Tile tl at level l = pooled q-rows tl*16..+15, all sharing k-block tl^1.
__global__ __launch_bounds__(64) void coarse_kernel(
    const _Float16* __restrict__ qp, const _Float16* __restrict__ kp,
    const _Float16* __restrict__ vp, float* __restrict__ yc, float* __restrict__ ac) {
    const int t = threadIdx.x, m = t & 15, quad = t >> 4;
    const int u = blockIdx.x, z = blockIdx.y;
    int l, tl, co;
    if (u < 16)      { l = 5; tl = u;      co = 0;   }
    else if (u < 24) { l = 6; tl = u - 16; co = 256; }
    else if (u < 28) { l = 7; tl = u - 24; co = 384; }
    else             { l = 8; tl = u - 28; co = 448; }
    const int kb = tl ^ 1;
    const size_t zp8 = (size_t)z * ROWS_CMP * DIM;

    const uint4a* qr = (const uint4a*)(qp + zp8 + (size_t)(OFF8[l] + tl * 16 + m) * DIM);
    const v8h qf0 = __builtin_bit_cast(v8h, qr[quad]);
    const v8h qf1 = __builtin_bit_cast(v8h, qr[4 + quad]);
    const uint4a* kr = (const uint4a*)(kp + zp8 + (size_t)(OFF8[l] + kb * 16 + m) * DIM);
    const v8h kf0 = __builtin_bit_cast(v8h, kr[quad]);
    const v8h kf1 = __builtin_bit_cast(v8h, kr[4 + quad]);
    const _Float16* vb = vp + zp8 + (size_t)(OFF8[l] + kb * 16) * DIM;
    uint2 vfr[4];
#pragma unroll
    for (int nt = 0; nt < 4; ++nt)
        vfr[nt] = *(const uint2a*)(vb + (nt * 16 + m) * 16 + quad * 4);

    v4f s4 = (v4f){0.f, 0.f, 0.f, 0.f};
    s4 = __builtin_amdgcn_mfma_f32_16x16x32_f16(kf0, qf0, s4, 0, 0, 0);
    s4 = __builtin_amdgcn_mfma_f32_16x16x32_f16(kf1, qf1, s4, 0, 0, 0);
    float mx = fmaxf(fmaxf(s4[0], s4[1]), fmaxf(s4[2], s4[3]));
    mx = fmaxf(mx, __shfl_xor(mx, 16, 64));
    mx = fmaxf(mx, __shfl_xor(mx, 32, 64));
    float e0 = __expf(s4[0] - mx), e1 = __expf(s4[1] - mx);
    float e2 = __expf(s4[2] - mx), e3 = __expf(s4[3] - mx);
    float sm = e0 + e1 + e2 + e3;
    sm += __shfl_xor(sm, 16, 64);
    sm += __shfl_xor(sm, 32, 64);
    const int sl = m + (quad << 4);  // 16 distinct q-rows: l=0 pattern
    v4h pf;
    pf[0] = (_Float16)bperm(sl, e0);
    pf[1] = (_Float16)bperm(sl, e1);
    pf[2] = (_Float16)bperm(sl, e2);
    pf[3] = (_Float16)bperm(sl, e3);
    v4f Yt[4];
#pragma unroll
    for (int nt = 0; nt < 4; ++nt) {
        Yt[nt] = (v4f){0.f, 0.f, 0.f, 0.f};
        Yt[nt] = __builtin_amdgcn_mfma_f32_16x16x16f16(pf, __builtin_bit_cast(v4h, vfr[nt]),
                                                       Yt[nt], 0, 0, 0);
    }
    float Ar[4];
#pragma unroll
    for (int r = 0; r < 4; ++r) Ar[r] = bperm(quad * 4 + r, sm);

    float* yb = yc + ((size_t)z * YROWS + co + tl * 16) * 64;
#pragma unroll
    for (int r = 0; r < 4; ++r)
#pragma unroll
        for (int nt = 0; nt < 4; ++nt)
            yb[(quad * 4 + r) * 64 + nt * 16 + m] = Yt[nt][r];
    if (m == 0) {
#pragma unroll
        for (int r = 0; r < 4; ++r)
            ac[(size_t)z * YROWS + co + tl * 16 + quad * 4 + r] = Ar[r];
    }
}

extern "C" void kernel_launch(void* const* d_in, const int* in_sizes, int n_in,
                              void* d_out, int out_size, void* d_ws, size_t ws_size,
                              hipStream_t stream) {
    const float* q = (const float*)d_in[0];
    const float* k = (const float*)d_in[1];
    const float* v = (const float*)d_in[2];
    float* out = (float*)d_out;

    const size_t T8 = (size_t)NBH * ROWS_CMP * DIM * sizeof(_Float16);  // 33,423,360
    const size_t YCB = (size_t)NBH * YROWS * 64 * sizeof(float);        // 3,932,160
    const size_t ACB = (size_t)NBH * YROWS * sizeof(float);             // 61,440
    char* wsp = (char*)d_ws;
    _Float16* qp = (_Float16*)wsp;
    _Float16* kp = (_Float16*)(wsp + T8);
    _Float16* vp = (_Float16*)(wsp + 2 * T8);

    pool_kernel<<<dim3(SEQN / 256 / NC, NBH, 3), 256, 0, stream>>>(q, k, v, qp, kp, vp);
    if (ws_size >= 3 * T8 + YCB + ACB) {
        float* yc = (float*)(wsp + 3 * T8);
        float* ac = (float*)(wsp + 3 * T8 + YCB);
        coarse_kernel<<<dim3(30, NBH), 64, 0, stream>>>(qp, kp, vp, yc, ac);
        attend_kernel<true><<<dim3(SEQN / 64, NBH), 256, 0, stream>>>(q, k, v, qp, kp, vp, yc,
                                                                      ac, out);
    } else {
        attend_kernel<false><<<dim3(SEQN / 64, NBH), 256, 0, stream>>>(q, k, v, qp, kp, vp,
                                                                       nullptr, nullptr, out);
    }
}